// Round 2
// baseline (684.385 us; speedup 1.0000x reference)
//
#include <hip/hip_runtime.h>

#define B 16
#define C 512
#define HW 4096
#define KK 49

// ---------------- workspace layout (floats) ----------------
// kwT   [512][64]      K_w transposed (c-major), rows padded to 64
// c0wT  [512][512]     conv0_w transposed -> [c][o]
// c1wT  [512][512]     conv1_w transposed -> [c][o]
// keyraw[B][49][4096]
// stats [B][49][2]     (max, 1/sumexp)
// ksmT  [B][4096][64]  softmaxed key, transposed, rows padded to 64 (cols>=49 zero)
// fpart [8][B][512][49]
// fsum  [B][512][49]
// t0    [B][512][49]
// g     [B][512][49]
// t1    [B][512][49]
#define OFF_KWT    0
#define OFF_C0WT   32768
#define OFF_C1WT   294912
#define OFF_KEYRAW 557056
#define OFF_STATS  3768320
#define OFF_KSMT   3769888
#define OFF_FPART  7964192
#define OFF_FSUM   11175456
#define OFF_T0     11576864
#define OFF_G      11978272
#define OFF_T1     12379680
// total 12,781,088 floats = 51.1 MB

// k0: transpose the three weight matrices (tiny, one-shot)
__global__ __launch_bounds__(256) void k0_transpose(
    const float* __restrict__ K_w, const float* __restrict__ c0w,
    const float* __restrict__ c1w, float* __restrict__ kwT,
    float* __restrict__ c0wT, float* __restrict__ c1wT) {
  int i = blockIdx.x * 256 + threadIdx.x;
  if (i < 512 * KK) {
    int cc = i / KK, oo = i % KK;
    kwT[cc * 64 + oo] = K_w[oo * 512 + cc];
  }
  if (i < 512 * 512) {
    int cc = i >> 9, oo = i & 511;
    c0wT[i] = c0w[oo * 512 + cc];
    c1wT[i] = c1w[oo * 512 + cc];
  }
}

// k1: keyraw[b][o][n] = sum_c K_w[o][c] * x[b][c][n] + K_b[o]
// lanes over n; K_w accesses are wave-uniform -> scalar loads
__global__ __launch_bounds__(256) void k1_key(
    const float* __restrict__ x, const float* __restrict__ kwT,
    const float* __restrict__ Kb, float* __restrict__ keyraw) {
  int b = blockIdx.y;
  int n = blockIdx.x * 256 + threadIdx.x;
  const float* xp = x + (size_t)(b * C) * HW + n;
  float acc[KK];
#pragma unroll
  for (int o = 0; o < KK; o++) acc[o] = 0.f;
  for (int c0 = 0; c0 < C; c0 += 8) {
    float xv[8];
#pragma unroll
    for (int u = 0; u < 8; u++) xv[u] = xp[(size_t)(c0 + u) * HW];
#pragma unroll
    for (int u = 0; u < 8; u++) {
      const float* kw = kwT + (c0 + u) * 64;
#pragma unroll
      for (int o = 0; o < KK; o++) acc[o] += xv[u] * kw[o];
    }
  }
#pragma unroll
  for (int o = 0; o < KK; o++)
    keyraw[(size_t)(b * KK + o) * HW + n] = acc[o] + Kb[o];
}

// k2a: per-(b,o) row max and 1/sumexp over n
__global__ __launch_bounds__(256) void k2a_stats(
    const float* __restrict__ keyraw, float* __restrict__ stats) {
  int row = blockIdx.x;  // b*49+o
  const float* p = keyraw + (size_t)row * HW;
  int tid = threadIdx.x;
  float4 v[4];
  float mx = -1e30f;
#pragma unroll
  for (int j = 0; j < 4; j++) {
    v[j] = ((const float4*)p)[tid + j * 256];
    mx = fmaxf(mx, fmaxf(fmaxf(v[j].x, v[j].y), fmaxf(v[j].z, v[j].w)));
  }
  for (int s = 32; s > 0; s >>= 1) mx = fmaxf(mx, __shfl_xor(mx, s));
  __shared__ float red[8];
  int wv = tid >> 6, ln = tid & 63;
  if (ln == 0) red[wv] = mx;
  __syncthreads();
  mx = fmaxf(fmaxf(red[0], red[1]), fmaxf(red[2], red[3]));
  float sm = 0.f;
#pragma unroll
  for (int j = 0; j < 4; j++)
    sm += expf(v[j].x - mx) + expf(v[j].y - mx) + expf(v[j].z - mx) +
          expf(v[j].w - mx);
  for (int s = 32; s > 0; s >>= 1) sm += __shfl_xor(sm, s);
  __syncthreads();
  if (ln == 0) red[4 + wv] = sm;
  __syncthreads();
  if (tid == 0) {
    float s4 = red[4] + red[5] + red[6] + red[7];
    stats[row * 2] = mx;
    stats[row * 2 + 1] = 1.f / s4;
  }
}

// k2b: write softmaxed key TRANSPOSED: ksmT[b][n][o] (row padded to 64, zeros past 49)
__global__ __launch_bounds__(256) void k2b_write(
    const float* __restrict__ keyraw, const float* __restrict__ stats,
    float* __restrict__ ksmT) {
  int b = blockIdx.y;
  int n0 = blockIdx.x * 256;
  int tid = threadIdx.x;
  __shared__ float t[KK][257];
  for (int o = 0; o < KK; o++) {
    float mx = stats[(b * KK + o) * 2];
    float ri = stats[(b * KK + o) * 2 + 1];
    float v = keyraw[(size_t)(b * KK + o) * HW + n0 + tid];
    t[o][tid] = expf(v - mx) * ri;
  }
  __syncthreads();
  for (int i = tid; i < 4096; i += 256) {  // 256 rows x 16 float4
    int nl = i >> 4, o4 = (i & 15) * 4;
    float4 w;
    w.x = (o4 < KK) ? t[o4][nl] : 0.f;
    w.y = (o4 + 1 < KK) ? t[o4 + 1][nl] : 0.f;
    w.z = (o4 + 2 < KK) ? t[o4 + 2][nl] : 0.f;
    w.w = (o4 + 3 < KK) ? t[o4 + 3][nl] : 0.f;
    ((float4*)(ksmT + (size_t)(b * HW + n0 + nl) * 64))[i & 15] = w;
  }
}

// k3: fpart[ks][b][c][o] = sum_{n in ks-range} x[b][c][n] * ksmT[b][n][o]
// lanes over c (x staged via LDS transpose); ksmT reads wave-uniform -> scalar
__global__ __launch_bounds__(256) void k3_filters(
    const float* __restrict__ x, const float* __restrict__ ksmT,
    float* __restrict__ fpart) {
  int ct = blockIdx.x;  // 0..1 (c-tile of 256)
  int ks = blockIdx.y;  // 0..7 (n-split)
  int b = blockIdx.z;
  int tid = threadIdx.x;
  int c0 = ct * 256;
  int nbase = ks * 512;
  // stride 261: 261%32=5 -> staging-write banks (20*nq+5j+cl)%32, <=2 lanes/bank (free)
  __shared__ float xT[32][261];
  float acc[KK];
#pragma unroll
  for (int o = 0; o < KK; o++) acc[o] = 0.f;
  for (int n0 = nbase; n0 < nbase + 512; n0 += 32) {
#pragma unroll
    for (int k = 0; k < 8; k++) {
      int i = tid + k * 256;   // 2048 float4 slots: 256c x 8(n/4)
      int cl = i >> 3, nq = i & 7;
      float4 v = *(const float4*)(x + (size_t)(b * C + c0 + cl) * HW + n0 + nq * 4);
      xT[nq * 4 + 0][cl] = v.x;
      xT[nq * 4 + 1][cl] = v.y;
      xT[nq * 4 + 2][cl] = v.z;
      xT[nq * 4 + 3][cl] = v.w;
    }
    __syncthreads();
#pragma unroll 4
    for (int nn = 0; nn < 32; nn++) {
      float xv = xT[nn][tid];
      const float* kp = ksmT + (size_t)(b * HW + n0 + nn) * 64;
#pragma unroll
      for (int o = 0; o < KK; o++) acc[o] += xv * kp[o];
    }
    __syncthreads();
  }
  float* outp = fpart + ((size_t)(ks * B + b) * C + c0 + tid) * KK;
#pragma unroll
  for (int o = 0; o < KK; o++) outp[o] = acc[o];
}

// k3s: fsum = sum over 8 k-split partials
__global__ __launch_bounds__(256) void k3_sum(
    const float* __restrict__ fpart, float* __restrict__ fsum) {
  int i = blockIdx.x * 256 + threadIdx.x;  // float4 slot, 100352 total
  const int stride = B * C * KK / 4;
  float4 s = ((const float4*)fpart)[i];
#pragma unroll
  for (int k = 1; k < 8; k++) {
    float4 v = ((const float4*)fpart)[i + k * stride];
    s.x += v.x; s.y += v.y; s.z += v.z; s.w += v.w;
  }
  ((float4*)fsum)[i] = s;
}

// k4_gemm: out[b][o][ij] = sum_c wT[c][o] * fin[b][c][ij] + bias[o]
// lanes over ij (49 of 64 active), o-tile 16/block, wave-split over c + LDS reduce
__global__ __launch_bounds__(256) void k4_gemm(
    const float* __restrict__ fin, const float* __restrict__ wT,
    const float* __restrict__ bias, float* __restrict__ outp) {
  int og = blockIdx.x;  // 0..31
  int b = blockIdx.y;
  int tid = threadIdx.x, wv = tid >> 6, ln = tid & 63;
  bool act = ln < KK;
  float acc[16];
#pragma unroll
  for (int k = 0; k < 16; k++) acc[k] = 0.f;
  for (int c = wv * 128; c < wv * 128 + 128; c++) {
    float f = act ? fin[(size_t)(b * C + c) * KK + ln] : 0.f;
    const float* w = wT + (size_t)c * C + og * 16;
#pragma unroll
    for (int k = 0; k < 16; k++) acc[k] += f * w[k];
  }
  __shared__ float red[4][64][17];
#pragma unroll
  for (int k = 0; k < 16; k++) red[wv][ln][k] = acc[k];
  __syncthreads();
  if (wv == 0 && act) {
#pragma unroll
    for (int k = 0; k < 16; k++) {
      float s = red[0][ln][k] + red[1][ln][k] + red[2][ln][k] + red[3][ln][k] +
                bias[og * 16 + k];
      outp[(size_t)(b * C + og * 16 + k) * KK + ln] = s;
    }
  }
}

// k4_ln: per-b LayerNorm over 25088 elems + relu -> g
__global__ __launch_bounds__(256) void k4_ln(
    const float* __restrict__ t0, const float* __restrict__ lnw,
    const float* __restrict__ lnb, float* __restrict__ g) {
  int b = blockIdx.x, tid = threadIdx.x;
  const int NE = C * KK;  // 25088
  const float* p = t0 + (size_t)b * NE;
  float s = 0.f, q = 0.f;
  for (int i = tid; i < NE / 4; i += 256) {
    float4 v = ((const float4*)p)[i];
    s += v.x + v.y + v.z + v.w;
    q += v.x * v.x + v.y * v.y + v.z * v.z + v.w * v.w;
  }
  for (int sh = 32; sh > 0; sh >>= 1) {
    s += __shfl_xor(s, sh);
    q += __shfl_xor(q, sh);
  }
  __shared__ float rs[4], rq[4];
  int wv = tid >> 6, ln = tid & 63;
  if (ln == 0) { rs[wv] = s; rq[wv] = q; }
  __syncthreads();
  s = rs[0] + rs[1] + rs[2] + rs[3];
  q = rq[0] + rq[1] + rq[2] + rq[3];
  float mean = s / NE;
  float var = q / NE - mean * mean;
  float rstd = rsqrtf(var + 1e-5f);
  float* go = g + (size_t)b * NE;
  for (int i = tid; i < NE; i += 256) {
    float v = (p[i] - mean) * rstd * lnw[i] + lnb[i];
    go[i] = fmaxf(v, 0.f);
  }
}

// k5: depthwise 7x7, zero-pad 3; one block per (c,b) plane; 4x4 reg tile/thread
__global__ __launch_bounds__(256) void k5_dwconv(
    const float* __restrict__ x, const float* __restrict__ filt,
    float* __restrict__ outp) {
  int c = blockIdx.x, b = blockIdx.y, tid = threadIdx.x;
  __shared__ float xs[70][76];
  for (int i = tid; i < 70 * 19; i += 256)
    ((float4*)&xs[0][0])[i] = make_float4(0.f, 0.f, 0.f, 0.f);
  __syncthreads();
  const float* xp = x + (size_t)(b * C + c) * HW;
  for (int i = tid; i < 1024; i += 256) {
    int r = i >> 4, c4 = (i & 15) * 4;
    float4 v = ((const float4*)(xp + r * 64))[i & 15];
    xs[3 + r][3 + c4 + 0] = v.x;
    xs[3 + r][3 + c4 + 1] = v.y;
    xs[3 + r][3 + c4 + 2] = v.z;
    xs[3 + r][3 + c4 + 3] = v.w;
  }
  const float* fp = filt + (size_t)(b * C + c) * KK;
  float f[KK];
#pragma unroll
  for (int k = 0; k < KK; k++) f[k] = fp[k];
  __syncthreads();
  int tr = (tid >> 4) * 4, tc = (tid & 15) * 4;
  float acc[4][4];
#pragma unroll
  for (int r = 0; r < 4; r++)
#pragma unroll
    for (int j = 0; j < 4; j++) acc[r][j] = 0.f;
#pragma unroll
  for (int ii = 0; ii < 10; ii++) {
    float v[12];
#pragma unroll
    for (int q = 0; q < 3; q++) {
      float4 t4 = *(const float4*)&xs[tr + ii][tc + q * 4];
      v[q * 4 + 0] = t4.x; v[q * 4 + 1] = t4.y;
      v[q * 4 + 2] = t4.z; v[q * 4 + 3] = t4.w;
    }
#pragma unroll
    for (int rr = 0; rr < 4; rr++) {
      int kr = ii - rr;
      if (kr >= 0 && kr < 7) {
#pragma unroll
        for (int jj = 0; jj < 4; jj++)
#pragma unroll
          for (int kc = 0; kc < 7; kc++)
            acc[rr][jj] += f[kr * 7 + kc] * v[jj + kc];
      }
    }
  }
  float* op = outp + (size_t)(b * C + c) * HW;
#pragma unroll
  for (int rr = 0; rr < 4; rr++) {
    float4 w = make_float4(acc[rr][0], acc[rr][1], acc[rr][2], acc[rr][3]);
    *(float4*)(op + (tr + rr) * 64 + tc) = w;
  }
}

extern "C" void kernel_launch(void* const* d_in, const int* in_sizes, int n_in,
                              void* d_out, int out_size, void* d_ws,
                              size_t ws_size, hipStream_t stream) {
  const float* x   = (const float*)d_in[0];
  const float* K_w = (const float*)d_in[1];
  const float* K_b = (const float*)d_in[2];
  const float* c0w = (const float*)d_in[3];
  const float* c0b = (const float*)d_in[4];
  const float* lnw = (const float*)d_in[5];
  const float* lnb = (const float*)d_in[6];
  const float* c1w = (const float*)d_in[7];
  const float* c1b = (const float*)d_in[8];
  float* outp = (float*)d_out;
  float* ws = (float*)d_ws;

  float* kwT    = ws + OFF_KWT;
  float* c0wT   = ws + OFF_C0WT;
  float* c1wT   = ws + OFF_C1WT;
  float* keyraw = ws + OFF_KEYRAW;
  float* stats  = ws + OFF_STATS;
  float* ksmT   = ws + OFF_KSMT;
  float* fpart  = ws + OFF_FPART;
  float* fsum   = ws + OFF_FSUM;
  float* t0     = ws + OFF_T0;
  float* g      = ws + OFF_G;
  float* t1     = ws + OFF_T1;

  k0_transpose<<<1024, 256, 0, stream>>>(K_w, c0w, c1w, kwT, c0wT, c1wT);
  k1_key<<<dim3(16, 16), 256, 0, stream>>>(x, kwT, K_b, keyraw);
  k2a_stats<<<B * KK, 256, 0, stream>>>(keyraw, stats);
  k2b_write<<<dim3(16, 16), 256, 0, stream>>>(keyraw, stats, ksmT);
  k3_filters<<<dim3(2, 8, 16), 256, 0, stream>>>(x, ksmT, fpart);
  k3_sum<<<392, 256, 0, stream>>>(fpart, fsum);
  k4_gemm<<<dim3(32, 16), 256, 0, stream>>>(fsum, c0wT, c0b, t0);
  k4_ln<<<16, 256, 0, stream>>>(t0, lnw, lnb, g);
  k4_gemm<<<dim3(32, 16), 256, 0, stream>>>(g, c1wT, c1b, t1);
  k5_dwconv<<<dim3(C, B), 256, 0, stream>>>(x, t1, outp);
}

// Round 3
// 523.378 us; speedup vs baseline: 1.3076x; 1.3076x over previous
//
#include <hip/hip_runtime.h>

#define B 16
#define C 512
#define HW 4096
#define KK 49

// ---------------- workspace layout (floats), with lifetime overlaps ----------
// kwT    [512][64]        0         (32768)
// c0wT   [512][512]       32768     (262144)
// c1wT   [512][512]       294912    (262144)
// stats  [B][49][2]       557056    (1568)
// keyraw [B][49][4096]    558624    (3211264)   dead after k2b
//   fsum [B][512][49]     558624    (401408)    written by k3_sum (after k2b)
//   t0   [B][512][49]     960032
//   g    [B][512][49]     1361440
//   t1   [B][512][49]     1762848
// ksmT   [B][4096][64]    3769888   (4194304)   dead after k3
// kpart  [4][B][49][4096] 7964192   (12845056)  dead after k1s_sum
//   fpart[32][B][512][49] 7964192   (12845056)  written by k3 (after k1s)
// total 20,809,248 floats = 83.2 MB
#define OFF_KWT    0
#define OFF_C0WT   32768
#define OFF_C1WT   294912
#define OFF_STATS  557056
#define OFF_KEYRAW 558624
#define OFF_FSUM   558624
#define OFF_T0     960032
#define OFF_G      1361440
#define OFF_T1     1762848
#define OFF_KSMT   3769888
#define OFF_KPART  7964192
#define OFF_FPART  7964192

// k0: transpose the three weight matrices (tiny, one-shot)
__global__ __launch_bounds__(256) void k0_transpose(
    const float* __restrict__ K_w, const float* __restrict__ c0w,
    const float* __restrict__ c1w, float* __restrict__ kwT,
    float* __restrict__ c0wT, float* __restrict__ c1wT) {
  int i = blockIdx.x * 256 + threadIdx.x;
  if (i < 512 * KK) {
    int cc = i / KK, oo = i % KK;
    kwT[cc * 64 + oo] = K_w[oo * 512 + cc];
  }
  if (i < 512 * 512) {
    int cc = i >> 9, oo = i & 511;
    c0wT[i] = c0w[oo * 512 + cc];
    c1wT[i] = c1w[oo * 512 + cc];
  }
}

// k1: kpart[cs][b][o][n] = sum_{c in cs-chunk} K_w[o][c] * x[b][c][n]
// 4-way c-split -> 1024 blocks = 4 waves/SIMD (was 1: latency-bound at 196us)
__global__ __launch_bounds__(256) void k1_key(
    const float* __restrict__ x, const float* __restrict__ kwT,
    float* __restrict__ kpart) {
  int b = blockIdx.y;
  int cs = blockIdx.z;  // 0..3, 128 channels each
  int n = blockIdx.x * 256 + threadIdx.x;
  const float* xp = x + ((size_t)(b * C) + cs * 128) * HW + n;
  float acc[KK];
#pragma unroll
  for (int o = 0; o < KK; o++) acc[o] = 0.f;
  for (int c0 = 0; c0 < 128; c0 += 8) {
    float xv[8];
#pragma unroll
    for (int u = 0; u < 8; u++) xv[u] = xp[(size_t)(c0 + u) * HW];
#pragma unroll
    for (int u = 0; u < 8; u++) {
      const float* kw = kwT + (cs * 128 + c0 + u) * 64;  // wave-uniform -> s_load
#pragma unroll
      for (int o = 0; o < KK; o++) acc[o] += xv[u] * kw[o];
    }
  }
#pragma unroll
  for (int o = 0; o < KK; o++)
    kpart[((size_t)(cs * B + b) * KK + o) * HW + n] = acc[o];
}

// k1s: keyraw = sum of 4 c-split partials + bias
__global__ __launch_bounds__(256) void k1s_sum(
    const float* __restrict__ kpart, const float* __restrict__ Kb,
    float* __restrict__ keyraw) {
  int i = blockIdx.x * 256 + threadIdx.x;  // float4 slot, B*KK*HW/4 = 802816
  const int stride = B * KK * HW / 4;
  float4 s = ((const float4*)kpart)[i];
#pragma unroll
  for (int k = 1; k < 4; k++) {
    float4 v = ((const float4*)kpart)[i + k * stride];
    s.x += v.x; s.y += v.y; s.z += v.z; s.w += v.w;
  }
  int o = (i >> 10) % KK;  // i*4/HW = row (b*49+o); HW/4=1024
  float bb = Kb[o];
  s.x += bb; s.y += bb; s.z += bb; s.w += bb;
  ((float4*)keyraw)[i] = s;
}

// k2a: per-(b,o) row max and 1/sumexp over n
__global__ __launch_bounds__(256) void k2a_stats(
    const float* __restrict__ keyraw, float* __restrict__ stats) {
  int row = blockIdx.x;  // b*49+o
  const float* p = keyraw + (size_t)row * HW;
  int tid = threadIdx.x;
  float4 v[4];
  float mx = -1e30f;
#pragma unroll
  for (int j = 0; j < 4; j++) {
    v[j] = ((const float4*)p)[tid + j * 256];
    mx = fmaxf(mx, fmaxf(fmaxf(v[j].x, v[j].y), fmaxf(v[j].z, v[j].w)));
  }
  for (int s = 32; s > 0; s >>= 1) mx = fmaxf(mx, __shfl_xor(mx, s));
  __shared__ float red[8];
  int wv = tid >> 6, ln = tid & 63;
  if (ln == 0) red[wv] = mx;
  __syncthreads();
  mx = fmaxf(fmaxf(red[0], red[1]), fmaxf(red[2], red[3]));
  float sm = 0.f;
#pragma unroll
  for (int j = 0; j < 4; j++)
    sm += expf(v[j].x - mx) + expf(v[j].y - mx) + expf(v[j].z - mx) +
          expf(v[j].w - mx);
  for (int s = 32; s > 0; s >>= 1) sm += __shfl_xor(sm, s);
  __syncthreads();
  if (ln == 0) red[4 + wv] = sm;
  __syncthreads();
  if (tid == 0) {
    float s4 = red[4] + red[5] + red[6] + red[7];
    stats[row * 2] = mx;
    stats[row * 2 + 1] = 1.f / s4;
  }
}

// k2b: write softmaxed key TRANSPOSED: ksmT[b][n][o] (row padded to 64, zeros past 49)
__global__ __launch_bounds__(256) void k2b_write(
    const float* __restrict__ keyraw, const float* __restrict__ stats,
    float* __restrict__ ksmT) {
  int b = blockIdx.y;
  int n0 = blockIdx.x * 256;
  int tid = threadIdx.x;
  __shared__ float t[KK][257];
  for (int o = 0; o < KK; o++) {
    float mx = stats[(b * KK + o) * 2];
    float ri = stats[(b * KK + o) * 2 + 1];
    float v = keyraw[(size_t)(b * KK + o) * HW + n0 + tid];
    t[o][tid] = expf(v - mx) * ri;
  }
  __syncthreads();
  for (int i = tid; i < 4096; i += 256) {  // 256 rows x 16 float4
    int nl = i >> 4, o4 = (i & 15) * 4;
    float4 w;
    w.x = (o4 < KK) ? t[o4][nl] : 0.f;
    w.y = (o4 + 1 < KK) ? t[o4 + 1][nl] : 0.f;
    w.z = (o4 + 2 < KK) ? t[o4 + 2][nl] : 0.f;
    w.w = (o4 + 3 < KK) ? t[o4 + 3][nl] : 0.f;
    ((float4*)(ksmT + (size_t)(b * HW + n0 + nl) * 64))[i & 15] = w;
  }
}

// k3: fpart[ks][b][c][o] = sum_{n in ks-range(128)} x[b][c][n] * ksmT[b][n][o]
// 32-way n-split -> 1024 blocks; LDS 33.4KB -> 4 blocks/CU = 4 waves/SIMD
__global__ __launch_bounds__(256) void k3_filters(
    const float* __restrict__ x, const float* __restrict__ ksmT,
    float* __restrict__ fpart) {
  int ct = blockIdx.x;  // 0..1 (c-tile of 256)
  int ks = blockIdx.y;  // 0..31 (n-split, 128 each)
  int b = blockIdx.z;
  int tid = threadIdx.x;
  int c0 = ct * 256;
  int nbase = ks * 128;
  // stride 261: 261%32=5 -> staging-write banks <=2 lanes/bank (free on CDNA4)
  __shared__ float xT[32][261];
  float acc[KK];
#pragma unroll
  for (int o = 0; o < KK; o++) acc[o] = 0.f;
  for (int n0 = nbase; n0 < nbase + 128; n0 += 32) {
#pragma unroll
    for (int k = 0; k < 8; k++) {
      int i = tid + k * 256;   // 2048 float4 slots: 256c x 8(n/4)
      int cl = i >> 3, nq = i & 7;
      float4 v = *(const float4*)(x + (size_t)(b * C + c0 + cl) * HW + n0 + nq * 4);
      xT[nq * 4 + 0][cl] = v.x;
      xT[nq * 4 + 1][cl] = v.y;
      xT[nq * 4 + 2][cl] = v.z;
      xT[nq * 4 + 3][cl] = v.w;
    }
    __syncthreads();
#pragma unroll 4
    for (int nn = 0; nn < 32; nn++) {
      float xv = xT[nn][tid];
      const float* kp = ksmT + (size_t)(b * HW + n0 + nn) * 64;  // uniform -> s_load
#pragma unroll
      for (int o = 0; o < KK; o++) acc[o] += xv * kp[o];
    }
    __syncthreads();
  }
  float* outp = fpart + ((size_t)(ks * B + b) * C + c0 + tid) * KK;
#pragma unroll
  for (int o = 0; o < KK; o++) outp[o] = acc[o];
}

// k3s: fsum = sum over 32 n-split partials
__global__ __launch_bounds__(256) void k3_sum(
    const float* __restrict__ fpart, float* __restrict__ fsum) {
  int i = blockIdx.x * 256 + threadIdx.x;  // float4 slot, 100352 total
  const int stride = B * C * KK / 4;
  float4 s = ((const float4*)fpart)[i];
#pragma unroll
  for (int k = 1; k < 32; k++) {
    float4 v = ((const float4*)fpart)[i + k * stride];
    s.x += v.x; s.y += v.y; s.z += v.z; s.w += v.w;
  }
  ((float4*)fsum)[i] = s;
}

// k4_gemm: out[b][o][ij] = sum_c wT[c][o] * fin[b][c][ij] + bias[o]
__global__ __launch_bounds__(256) void k4_gemm(
    const float* __restrict__ fin, const float* __restrict__ wT,
    const float* __restrict__ bias, float* __restrict__ outp) {
  int og = blockIdx.x;  // 0..31
  int b = blockIdx.y;
  int tid = threadIdx.x, wv = tid >> 6, ln = tid & 63;
  bool act = ln < KK;
  float acc[16];
#pragma unroll
  for (int k = 0; k < 16; k++) acc[k] = 0.f;
  for (int c = wv * 128; c < wv * 128 + 128; c++) {
    float f = act ? fin[(size_t)(b * C + c) * KK + ln] : 0.f;
    const float* w = wT + (size_t)c * C + og * 16;
#pragma unroll
    for (int k = 0; k < 16; k++) acc[k] += f * w[k];
  }
  __shared__ float red[4][64][17];
#pragma unroll
  for (int k = 0; k < 16; k++) red[wv][ln][k] = acc[k];
  __syncthreads();
  if (wv == 0 && act) {
#pragma unroll
    for (int k = 0; k < 16; k++) {
      float s = red[0][ln][k] + red[1][ln][k] + red[2][ln][k] + red[3][ln][k] +
                bias[og * 16 + k];
      outp[(size_t)(b * C + og * 16 + k) * KK + ln] = s;
    }
  }
}

// k4_ln: per-b LayerNorm over 25088 elems + relu -> g
__global__ __launch_bounds__(256) void k4_ln(
    const float* __restrict__ t0, const float* __restrict__ lnw,
    const float* __restrict__ lnb, float* __restrict__ g) {
  int b = blockIdx.x, tid = threadIdx.x;
  const int NE = C * KK;  // 25088
  const float* p = t0 + (size_t)b * NE;
  float s = 0.f, q = 0.f;
  for (int i = tid; i < NE / 4; i += 256) {
    float4 v = ((const float4*)p)[i];
    s += v.x + v.y + v.z + v.w;
    q += v.x * v.x + v.y * v.y + v.z * v.z + v.w * v.w;
  }
  for (int sh = 32; sh > 0; sh >>= 1) {
    s += __shfl_xor(s, sh);
    q += __shfl_xor(q, sh);
  }
  __shared__ float rs[4], rq[4];
  int wv = tid >> 6, ln = tid & 63;
  if (ln == 0) { rs[wv] = s; rq[wv] = q; }
  __syncthreads();
  s = rs[0] + rs[1] + rs[2] + rs[3];
  q = rq[0] + rq[1] + rq[2] + rq[3];
  float mean = s / NE;
  float var = q / NE - mean * mean;
  float rstd = rsqrtf(var + 1e-5f);
  float* go = g + (size_t)b * NE;
  for (int i = tid; i < NE; i += 256) {
    float v = (p[i] - mean) * rstd * lnw[i] + lnb[i];
    go[i] = fmaxf(v, 0.f);
  }
}

// k5: depthwise 7x7, zero-pad 3; one block per (c,b) plane; 4x4 reg tile/thread
__global__ __launch_bounds__(256) void k5_dwconv(
    const float* __restrict__ x, const float* __restrict__ filt,
    float* __restrict__ outp) {
  int c = blockIdx.x, b = blockIdx.y, tid = threadIdx.x;
  __shared__ float xs[70][76];
  for (int i = tid; i < 70 * 19; i += 256)
    ((float4*)&xs[0][0])[i] = make_float4(0.f, 0.f, 0.f, 0.f);
  __syncthreads();
  const float* xp = x + (size_t)(b * C + c) * HW;
  for (int i = tid; i < 1024; i += 256) {
    int r = i >> 4, c4 = (i & 15) * 4;
    float4 v = ((const float4*)(xp + r * 64))[i & 15];
    xs[3 + r][3 + c4 + 0] = v.x;
    xs[3 + r][3 + c4 + 1] = v.y;
    xs[3 + r][3 + c4 + 2] = v.z;
    xs[3 + r][3 + c4 + 3] = v.w;
  }
  const float* fp = filt + (size_t)(b * C + c) * KK;
  float f[KK];
#pragma unroll
  for (int k = 0; k < KK; k++) f[k] = fp[k];
  __syncthreads();
  int tr = (tid >> 4) * 4, tc = (tid & 15) * 4;
  float acc[4][4];
#pragma unroll
  for (int r = 0; r < 4; r++)
#pragma unroll
    for (int j = 0; j < 4; j++) acc[r][j] = 0.f;
#pragma unroll
  for (int ii = 0; ii < 10; ii++) {
    float v[12];
#pragma unroll
    for (int q = 0; q < 3; q++) {
      float4 t4 = *(const float4*)&xs[tr + ii][tc + q * 4];
      v[q * 4 + 0] = t4.x; v[q * 4 + 1] = t4.y;
      v[q * 4 + 2] = t4.z; v[q * 4 + 3] = t4.w;
    }
#pragma unroll
    for (int rr = 0; rr < 4; rr++) {
      int kr = ii - rr;
      if (kr >= 0 && kr < 7) {
#pragma unroll
        for (int jj = 0; jj < 4; jj++)
#pragma unroll
          for (int kc = 0; kc < 7; kc++)
            acc[rr][jj] += f[kr * 7 + kc] * v[jj + kc];
      }
    }
  }
  float* op = outp + (size_t)(b * C + c) * HW;
#pragma unroll
  for (int rr = 0; rr < 4; rr++) {
    float4 w = make_float4(acc[rr][0], acc[rr][1], acc[rr][2], acc[rr][3]);
    *(float4*)(op + (tr + rr) * 64 + tc) = w;
  }
}

extern "C" void kernel_launch(void* const* d_in, const int* in_sizes, int n_in,
                              void* d_out, int out_size, void* d_ws,
                              size_t ws_size, hipStream_t stream) {
  const float* x   = (const float*)d_in[0];
  const float* K_w = (const float*)d_in[1];
  const float* K_b = (const float*)d_in[2];
  const float* c0w = (const float*)d_in[3];
  const float* c0b = (const float*)d_in[4];
  const float* lnw = (const float*)d_in[5];
  const float* lnb = (const float*)d_in[6];
  const float* c1w = (const float*)d_in[7];
  const float* c1b = (const float*)d_in[8];
  float* outp = (float*)d_out;
  float* ws = (float*)d_ws;

  float* kwT    = ws + OFF_KWT;
  float* c0wT   = ws + OFF_C0WT;
  float* c1wT   = ws + OFF_C1WT;
  float* stats  = ws + OFF_STATS;
  float* keyraw = ws + OFF_KEYRAW;
  float* fsum   = ws + OFF_FSUM;
  float* t0     = ws + OFF_T0;
  float* g      = ws + OFF_G;
  float* t1     = ws + OFF_T1;
  float* ksmT   = ws + OFF_KSMT;
  float* kpart  = ws + OFF_KPART;
  float* fpart  = ws + OFF_FPART;

  k0_transpose<<<1024, 256, 0, stream>>>(K_w, c0w, c1w, kwT, c0wT, c1wT);
  k1_key<<<dim3(16, 16, 4), 256, 0, stream>>>(x, kwT, kpart);
  k1s_sum<<<3136, 256, 0, stream>>>(kpart, K_b, keyraw);
  k2a_stats<<<B * KK, 256, 0, stream>>>(keyraw, stats);
  k2b_write<<<dim3(16, 16), 256, 0, stream>>>(keyraw, stats, ksmT);
  k3_filters<<<dim3(2, 32, 16), 256, 0, stream>>>(x, ksmT, fpart);
  k3_sum<<<392, 256, 0, stream>>>(fpart, fsum);
  k4_gemm<<<dim3(32, 16), 256, 0, stream>>>(fsum, c0wT, c0b, t0);
  k4_ln<<<16, 256, 0, stream>>>(t0, lnw, lnb, g);
  k4_gemm<<<dim3(32, 16), 256, 0, stream>>>(g, c1wT, c1b, t1);
  k5_dwconv<<<dim3(C, B), 256, 0, stream>>>(x, t1, outp);
}